// Round 5
// baseline (222.128 us; speedup 1.0000x reference)
//
#include <hip/hip_runtime.h>

// ---------------- problem constants ----------------
constexpr int Bv = 2, Cv = 64, Hv = 192, Wv = 192;
constexpr int Hp = 194, Wp = 194;
constexpr int PLANE = Hp * Wp;            // 37636
constexpr int NCIN = 65;                  // 64 x-channels + depth
constexpr int Lv = Hv * Wv;               // 36864
constexpr int XP_SZ  = Bv * NCIN * PLANE; // padded input floats
constexpr int OFFH   = Bv * 9 * Lv;       // one partial buffer (floats) = 663552

typedef __attribute__((ext_vector_type(8))) short short8;
typedef __attribute__((ext_vector_type(4))) float f32x4;

__device__ __forceinline__ unsigned short f2b(float v) {
  unsigned u = __float_as_uint(v);
  u = (u + 0x7FFFu + ((u >> 16) & 1u)) >> 16;   // RNE
  return (unsigned short)u;
}

// ---------------- K0: build padded input ----------------
__global__ __launch_bounds__(256) void pad_kernel(
    const float* __restrict__ x, const float* __restrict__ depth,
    float* __restrict__ xp) {
  for (int idx = blockIdx.x * blockDim.x + threadIdx.x; idx < XP_SZ;
       idx += gridDim.x * blockDim.x) {
    int p  = idx % PLANE;
    int bc = idx / PLANE;
    int c  = bc % NCIN;
    int b  = bc / NCIN;
    int ph = p / Wp, pw = p % Wp;
    float v = 0.f;
    if (ph >= 1 && ph <= Hv && pw >= 1 && pw <= Wv) {
      int ih = ph - 1, iw = pw - 1;
      v = (c < Cv) ? x[((b * Cv + c) * Hv + ih) * Wv + iw]
                   : depth[(b * Hv + ih) * Wv + iw];
    }
    xp[idx] = v;
  }
}

// ---------------- K0b: prep (W -> bf16 t-major, wo -> transposed) --------
// Wb[o][t*64+c] = bf16(W[o][c*9+t])  (K permuted t-major; matches gather)
__global__ __launch_bounds__(256) void prep_kernel(
    const float* __restrict__ Wg, const float* __restrict__ wo,
    unsigned short* __restrict__ Wb, float* __restrict__ woT) {
  int n = blockIdx.x * 256 + threadIdx.x;
  if (n < 64 * 576) {
    int o = n / 576, r = n % 576;
    int t = r >> 6, c = r & 63;
    Wb[n] = f2b(Wg[o * 576 + c * 9 + t]);
  }
  if (n < 585 * 18) {                 // woT[ck][t2] = wo[t2][ck]
    int ck = n / 18, t2 = n - ck * 18;
    woT[n] = wo[t2 * 585 + ck];
  }
}

// ---------------- K1: offset conv, 8-way split (c x4, axis x2) -----------
// group g = axis*4 + cq; axis 0 -> t2 in [0,9), axis 1 -> t2 in [9,18)
// offp8[g][b][tt][l] partial sums; summed in main_kernel's staging phase.
__global__ __launch_bounds__(256) void offconv_kernel(
    const float* __restrict__ xp, const float* __restrict__ woT,
    float* __restrict__ offp8) {
  int bid = blockIdx.x;
  int g   = bid & 7;                  // XCD-aligned: each XCD owns one group
  int pb  = bid >> 3;                 // 0..287
  int axis = g >> 2, cq = g & 3;
  int c0  = cq * 16;
  int cnt = (cq == 3) ? 17 : 16;      // last quarter includes depth channel

  int P = pb * 256 + threadIdx.x;     // pixel id in [0, B*L)
  int b = P / Lv, l = P % Lv;
  int oh = l / Wv, ow = l % Wv;

  float acc[9];
#pragma unroll
  for (int t = 0; t < 9; ++t) acc[t] = 0.f;

  const float* xpb   = xp + (b * NCIN + c0) * PLANE + oh * Wp + ow;
  const float* wbase = woT + c0 * 9 * 18 + axis * 9;
  for (int cl = 0; cl < cnt; ++cl) {
    const float* xc = xpb + cl * PLANE;
#pragma unroll
    for (int kh = 0; kh < 3; ++kh)
#pragma unroll
      for (int kw = 0; kw < 3; ++kw) {
        float v = xc[kh * Wp + kw];
        const float* wr = wbase + (cl * 9 + kh * 3 + kw) * 18;  // uniform
#pragma unroll
        for (int tt = 0; tt < 9; ++tt) acc[tt] += v * wr[tt];
      }
  }
  float* op = offp8 + ((g * Bv + b) * 9) * Lv + l;
#pragma unroll
  for (int tt = 0; tt < 9; ++tt) op[tt * Lv] = acc[tt];
}

// ---------------- K2: fused meta + gather(bf16 cols) + MFMA --------------
// Block: 64 px x 64 out-ch, 4 waves. K t-major: chunk ch == tap t, 64 c's.
__global__ __launch_bounds__(256) void main_kernel(
    const float* __restrict__ xp, const unsigned short* __restrict__ Wb,
    const float* __restrict__ offp8, const float* __restrict__ bias,
    float* __restrict__ out) {
  int bid = blockIdx.x;
  int swz = (bid & 7) * 144 + (bid >> 3);   // XCD-contiguous tiles (1152%8==0)
  int b   = swz / 576;
  int l0  = (swz % 576) * 64;

  __shared__ int    s_mi[9 * 64];
  __shared__ float4 s_w4[9 * 64];
  __shared__ unsigned short s_cols[2][8][64][8];

  int tid = threadIdx.x;

  // ---- staging: combine 8 offset partials -> per-(t,px) metadata ----
  for (int e = tid; e < 576; e += 256) {
    int t = e >> 6, px_ = e & 63;
    int l = l0 + px_;
    int oh = l / Wv, ow = l % Wv;
    float ox = bias[t], oy = bias[9 + t];
#pragma unroll
    for (int q = 0; q < 4; ++q) {
      ox += offp8[((q * Bv + b) * 9 + t) * Lv + l];
      oy += offp8[(((q + 4) * Bv + b) * 9 + t) * Lv + l];
    }
    float cx = (float)(oh + t / 3) + ox;   // base(oh+1)+delta(t/3-1)+off
    float cy = (float)(ow + t % 3) + oy;
    cx = fminf(fmaxf(cx, 0.f), 193.f);
    cy = fminf(fmaxf(cy, 0.f), 193.f);
    int tlx = min((int)cx, 192);
    int tly = min((int)cy, 192);
    float fx = cx - (float)tlx, fy = cy - (float)tly;
    float ax = 1.f - fx, ay = 1.f - fy;
    s_mi[e] = tlx * Wp + tly;
    s_w4[e] = make_float4(ax * ay, ax * fy, fx * ay, fx * fy);
  }

  int px   = tid & 63;
  int lane = tid & 63;
  int iq   = __builtin_amdgcn_readfirstlane(tid >> 6);  // wave id 0..3
  int ow_  = (iq >> 1) * 32;     // wave o-offset
  int pw_  = (iq & 1) * 32;      // wave px-offset
  const float* xb = xp + b * NCIN * PLANE;

  f32x4 acc[2][2];
#pragma unroll
  for (int mt = 0; mt < 2; ++mt)
#pragma unroll
    for (int nt = 0; nt < 2; ++nt) acc[mt][nt] = (f32x4)0.f;

  __syncthreads();   // metadata ready

  // ---- gather one tap (64 channels) into s_cols[buf] ----
  // All 64 values of a chunk share (mi, w4); loads are uniform-base + mi.
  auto gather = [&](int t, int buf) {
    int    mi = s_mi[t * 64 + px];
    float4 w  = s_w4[t * 64 + px];
#pragma unroll
    for (int s = 0; s < 2; ++s) {
      int gi = iq * 2 + s;                 // c-group 0..7 (wave-uniform)
      short8 hv;
#pragma unroll
      for (int j = 0; j < 8; ++j) {
        const float* cp = xb + (gi * 8 + j) * PLANE;   // SGPR base
        float v = w.x * cp[mi]      + w.y * cp[mi + 1] +
                  w.z * cp[mi + Wp] + w.w * cp[mi + Wp + 1];
        hv[j] = (short)f2b(v);
      }
      *(short8*)&s_cols[buf][gi][px][0] = hv;
    }
  };

  gather(0, 0);
  __syncthreads();

  for (int ch = 0; ch < 9; ++ch) {
    int cur = ch & 1;
    if (ch < 8) gather(ch + 1, cur ^ 1);   // issue next-chunk loads first

    // ---- MFMA on buf[cur]: 2 K-steps x (2 o-tiles x 2 px-tiles) ----
#pragma unroll
    for (int ks = 0; ks < 2; ++ks) {
      int k = ch * 64 + ks * 32 + (lane >> 4) * 8;
      short8 a0 = *(const short8*)&Wb[(ow_ + (lane & 15)) * 576 + k];
      short8 a1 = *(const short8*)&Wb[(ow_ + 16 + (lane & 15)) * 576 + k];
      int kg = ks * 4 + (lane >> 4);
      short8 b0 = *(const short8*)&s_cols[cur][kg][pw_ + (lane & 15)][0];
      short8 b1 = *(const short8*)&s_cols[cur][kg][pw_ + 16 + (lane & 15)][0];
      acc[0][0] = __builtin_amdgcn_mfma_f32_16x16x32_bf16(a0, b0, acc[0][0], 0, 0, 0);
      acc[0][1] = __builtin_amdgcn_mfma_f32_16x16x32_bf16(a0, b1, acc[0][1], 0, 0, 0);
      acc[1][0] = __builtin_amdgcn_mfma_f32_16x16x32_bf16(a1, b0, acc[1][0], 0, 0, 0);
      acc[1][1] = __builtin_amdgcn_mfma_f32_16x16x32_bf16(a1, b1, acc[1][1], 0, 0, 0);
    }
    __syncthreads();
  }

  // ---- epilogue: D[o][px], row=(lane>>4)*4+j, col=lane&15 ----
  int rr = lane >> 4, cl = lane & 15;
#pragma unroll
  for (int mt = 0; mt < 2; ++mt)
#pragma unroll
    for (int nt = 0; nt < 2; ++nt)
#pragma unroll
      for (int j = 0; j < 4; ++j) {
        int o = ow_ + mt * 16 + rr * 4 + j;
        int l = l0 + pw_ + nt * 16 + cl;
        out[((size_t)(b * Cv + o)) * Lv + l] = acc[mt][nt][j];
      }
}

// ---------------- launch ----------------
extern "C" void kernel_launch(void* const* d_in, const int* in_sizes, int n_in,
                              void* d_out, int out_size, void* d_ws, size_t ws_size,
                              hipStream_t stream) {
  const float* x     = (const float*)d_in[0];
  const float* depth = (const float*)d_in[1];
  const float* wo    = (const float*)d_in[2];
  const float* bias  = (const float*)d_in[3];
  const float* wgt   = (const float*)d_in[4];
  float* out = (float*)d_out;

  float* xp    = (float*)d_ws;                      // XP_SZ
  float* offp8 = xp + XP_SZ;                        // 8 * OFFH
  float* woT   = offp8 + 8 * OFFH;                  // 10530 (pad to 10560)
  unsigned short* Wb = (unsigned short*)(woT + 10560);   // 36864 ushort

  pad_kernel<<<2048, 256, 0, stream>>>(x, depth, xp);
  prep_kernel<<<144, 256, 0, stream>>>(wgt, wo, Wb, woT);
  offconv_kernel<<<2304, 256, 0, stream>>>(xp, woT, offp8);
  main_kernel<<<1152, 256, 0, stream>>>(xp, Wb, offp8, bias, out);
}

// Round 6
// 194.625 us; speedup vs baseline: 1.1413x; 1.1413x over previous
//
#include <hip/hip_runtime.h>

// ---------------- problem constants ----------------
constexpr int Bv = 2, Cv = 64, Hv = 192, Wv = 192;
constexpr int Hp = 194, Wp = 194;
constexpr int PLANE = Hp * Wp;            // 37636
constexpr int NCIN = 65;                  // 64 x-channels + depth
constexpr int Lv = Hv * Wv;               // 36864
constexpr int XP_SZ  = Bv * NCIN * PLANE; // padded input floats
constexpr int OFFH   = Bv * 9 * Lv;       // one partial buffer (floats)

typedef __attribute__((ext_vector_type(8))) short short8;
typedef __attribute__((ext_vector_type(4))) float f32x4;

__device__ __forceinline__ unsigned short f2b(float v) {
  unsigned u = __float_as_uint(v);
  u = (u + 0x7FFFu + ((u >> 16) & 1u)) >> 16;   // RNE
  return (unsigned short)u;
}

// ---------------- K0: build padded input ----------------
__global__ __launch_bounds__(256) void pad_kernel(
    const float* __restrict__ x, const float* __restrict__ depth,
    float* __restrict__ xp) {
  for (int idx = blockIdx.x * blockDim.x + threadIdx.x; idx < XP_SZ;
       idx += gridDim.x * blockDim.x) {
    int p  = idx % PLANE;
    int bc = idx / PLANE;
    int c  = bc % NCIN;
    int b  = bc / NCIN;
    int ph = p / Wp, pw = p % Wp;
    float v = 0.f;
    if (ph >= 1 && ph <= Hv && pw >= 1 && pw <= Wv) {
      int ih = ph - 1, iw = pw - 1;
      v = (c < Cv) ? x[((b * Cv + c) * Hv + ih) * Wv + iw]
                   : depth[(b * Hv + ih) * Wv + iw];
    }
    xp[idx] = v;
  }
}

// ---------------- K0b: prep (W -> bf16 t-major, wo -> transposed) --------
// Wb[o][t*64+c] = bf16(W[o][c*9+t])
__global__ __launch_bounds__(256) void prep_kernel(
    const float* __restrict__ Wg, const float* __restrict__ wo,
    unsigned short* __restrict__ Wb, float* __restrict__ woT) {
  int n = blockIdx.x * 256 + threadIdx.x;
  if (n < 64 * 576) {
    int o = n / 576, r = n % 576;
    int t = r >> 6, c = r & 63;
    Wb[n] = f2b(Wg[o * 576 + c * 9 + t]);
  }
  if (n < 585 * 18) {                 // woT[ck][t2] = wo[t2][ck]
    int ck = n / 18, t2 = n - ck * 18;
    woT[n] = wo[t2 * 585 + ck];
  }
}

// ---------------- K1: offset conv, 8-way split (c x4, axis x2) -----------
__global__ __launch_bounds__(256) void offconv_kernel(
    const float* __restrict__ xp, const float* __restrict__ woT,
    float* __restrict__ offp8) {
  int bid = blockIdx.x;
  int g   = bid & 7;                  // XCD-aligned group
  int pb  = bid >> 3;                 // 0..287
  int axis = g >> 2, cq = g & 3;
  int c0  = cq * 16;
  int cnt = (cq == 3) ? 17 : 16;

  int P = pb * 256 + threadIdx.x;
  int b = P / Lv, l = P % Lv;
  int oh = l / Wv, ow = l % Wv;

  float acc[9];
#pragma unroll
  for (int t = 0; t < 9; ++t) acc[t] = 0.f;

  const float* xpb   = xp + (b * NCIN + c0) * PLANE + oh * Wp + ow;
  const float* wbase = woT + c0 * 9 * 18 + axis * 9;
  for (int cl = 0; cl < cnt; ++cl) {
    const float* xc = xpb + cl * PLANE;
#pragma unroll
    for (int kh = 0; kh < 3; ++kh)
#pragma unroll
      for (int kw = 0; kw < 3; ++kw) {
        float v = xc[kh * Wp + kw];
        const float* wr = wbase + (cl * 9 + kh * 3 + kw) * 18;
#pragma unroll
        for (int tt = 0; tt < 9; ++tt) acc[tt] += v * wr[tt];
      }
  }
  float* op = offp8 + ((g * Bv + b) * 9) * Lv + l;
#pragma unroll
  for (int tt = 0; tt < 9; ++tt) op[tt * Lv] = acc[tt];
}

// ---------------- K2: fused meta + gather + MFMA, 32-px tiles ------------
// Block: 64 o x 32 px, 4 waves (wave = 16o x 32px). Per-thread: one
// channel-octet x its px. T14: half-prefetch next chunk before MFMA.
__global__ __launch_bounds__(256) void main_kernel(
    const float* __restrict__ xp, const unsigned short* __restrict__ Wb,
    const float* __restrict__ offp8, const float* __restrict__ bias,
    float* __restrict__ out) {
  int bid = blockIdx.x;
  int swz = (bid & 7) * 288 + (bid >> 3);   // 2304 % 8 == 0, bijective
  int b   = swz / 1152;
  int l0  = (swz % 1152) * 32;

  __shared__ int    s_mi[9 * 32];
  __shared__ float4 s_w4[9 * 32];
  __shared__ unsigned short s_cols[2][8][32][8];

  int tid = threadIdx.x;

  // ---- staging: combine 8 offset partials -> per-(t,px) metadata ----
  for (int e = tid; e < 288; e += 256) {
    int t = e >> 5, pxl = e & 31;
    int l = l0 + pxl;
    int oh = l / Wv, ow = l % Wv;
    float ox = bias[t], oy = bias[9 + t];
#pragma unroll
    for (int q = 0; q < 4; ++q) {
      ox += offp8[((q * Bv + b) * 9 + t) * Lv + l];
      oy += offp8[(((q + 4) * Bv + b) * 9 + t) * Lv + l];
    }
    float cx = (float)(oh + t / 3) + ox;
    float cy = (float)(ow + t % 3) + oy;
    cx = fminf(fmaxf(cx, 0.f), 193.f);
    cy = fminf(fmaxf(cy, 0.f), 193.f);
    int tlx = min((int)cx, 192);
    int tly = min((int)cy, 192);
    float fx = cx - (float)tlx, fy = cy - (float)tly;
    float ax = 1.f - fx, ay = 1.f - fy;
    s_mi[e] = tlx * Wp + tly;
    s_w4[e] = make_float4(ax * ay, ax * fy, fx * ay, fx * fy);
  }

  int px   = tid & 31;
  int cg   = tid >> 5;               // channel-octet 0..7
  int lane = tid & 63;
  int iq   = __builtin_amdgcn_readfirstlane(tid >> 6);  // wave 0..3
  int o0   = iq * 16;
  const float* xb = xp + (size_t)(b * NCIN + cg * 8) * PLANE;

  f32x4 acc[2];
  acc[0] = (f32x4)0.f;
  acc[1] = (f32x4)0.f;

  __syncthreads();

  // ---- prologue: gather chunk 0 inline ----
  {
    int    mi = s_mi[px];
    float4 w  = s_w4[px];
    short8 hv;
#pragma unroll
    for (int j = 0; j < 8; ++j) {
      const float* cp = xb + j * PLANE;
      float v = w.x * cp[mi]      + w.y * cp[mi + 1] +
                w.z * cp[mi + Wp] + w.w * cp[mi + Wp + 1];
      hv[j] = (short)f2b(v);
    }
    *(short8*)&s_cols[0][cg][px][0] = hv;
  }
  __syncthreads();

  for (int ch = 0; ch < 9; ++ch) {
    int cur = ch & 1;
    int    mi = 0;
    float4 w  = make_float4(0.f, 0.f, 0.f, 0.f);
    float  pf[4][4];

    // ---- T14 phase A: issue first-half loads of chunk ch+1 ----
    if (ch < 8) {
      mi = s_mi[(ch + 1) * 32 + px];
      w  = s_w4[(ch + 1) * 32 + px];
#pragma unroll
      for (int j = 0; j < 4; ++j) {
        const float* cp = xb + j * PLANE;
        pf[j][0] = cp[mi];      pf[j][1] = cp[mi + 1];
        pf[j][2] = cp[mi + Wp]; pf[j][3] = cp[mi + Wp + 1];
      }
    }

    // ---- MFMA on buf[cur] (loads in flight above) ----
#pragma unroll
    for (int ks = 0; ks < 2; ++ks) {
      int k = ch * 64 + ks * 32 + (lane >> 4) * 8;
      short8 a  = *(const short8*)&Wb[(o0 + (lane & 15)) * 576 + k];
      int kg = ks * 4 + (lane >> 4);
      short8 b0 = *(const short8*)&s_cols[cur][kg][lane & 15][0];
      short8 b1 = *(const short8*)&s_cols[cur][kg][16 + (lane & 15)][0];
      acc[0] = __builtin_amdgcn_mfma_f32_16x16x32_bf16(a, b0, acc[0], 0, 0, 0);
      acc[1] = __builtin_amdgcn_mfma_f32_16x16x32_bf16(a, b1, acc[1], 0, 0, 0);
    }

    // ---- T14 phase B: second-half loads, lerp landed half, write ----
    if (ch < 8) {
      float sf[4][4];
#pragma unroll
      for (int j = 0; j < 4; ++j) {
        const float* cp = xb + (4 + j) * PLANE;
        sf[j][0] = cp[mi];      sf[j][1] = cp[mi + 1];
        sf[j][2] = cp[mi + Wp]; sf[j][3] = cp[mi + Wp + 1];
      }
      short8 hv;
#pragma unroll
      for (int j = 0; j < 4; ++j)
        hv[j] = (short)f2b(w.x * pf[j][0] + w.y * pf[j][1] +
                           w.z * pf[j][2] + w.w * pf[j][3]);
#pragma unroll
      for (int j = 0; j < 4; ++j)
        hv[4 + j] = (short)f2b(w.x * sf[j][0] + w.y * sf[j][1] +
                               w.z * sf[j][2] + w.w * sf[j][3]);
      *(short8*)&s_cols[cur ^ 1][cg][px][0] = hv;
    }
    __syncthreads();
  }

  // ---- epilogue: D[o][px], row=(lane>>4)*4+j, col=lane&15 ----
  int rr = lane >> 4, cl = lane & 15;
#pragma unroll
  for (int nt = 0; nt < 2; ++nt)
#pragma unroll
    for (int j = 0; j < 4; ++j) {
      int o = o0 + rr * 4 + j;
      int l = l0 + nt * 16 + cl;
      out[((size_t)(b * Cv + o)) * Lv + l] = acc[nt][j];
    }
}

// ---------------- launch ----------------
extern "C" void kernel_launch(void* const* d_in, const int* in_sizes, int n_in,
                              void* d_out, int out_size, void* d_ws, size_t ws_size,
                              hipStream_t stream) {
  const float* x     = (const float*)d_in[0];
  const float* depth = (const float*)d_in[1];
  const float* wo    = (const float*)d_in[2];
  const float* bias  = (const float*)d_in[3];
  const float* wgt   = (const float*)d_in[4];
  float* out = (float*)d_out;

  float* xp    = (float*)d_ws;                      // XP_SZ
  float* offp8 = xp + XP_SZ;                        // 8 * OFFH
  float* woT   = offp8 + 8 * OFFH;                  // 10530 (pad to 10560)
  unsigned short* Wb = (unsigned short*)(woT + 10560);   // 36864 ushort

  pad_kernel<<<2048, 256, 0, stream>>>(x, depth, xp);
  prep_kernel<<<144, 256, 0, stream>>>(wgt, wo, Wb, woT);
  offconv_kernel<<<2304, 256, 0, stream>>>(xp, woT, offp8);
  main_kernel<<<2304, 256, 0, stream>>>(xp, Wb, offp8, bias, out);
}

// Round 7
// 189.660 us; speedup vs baseline: 1.1712x; 1.0262x over previous
//
#include <hip/hip_runtime.h>

// ---------------- problem constants ----------------
constexpr int Bv = 2, Cv = 64, Hv = 192, Wv = 192;
constexpr int Hp = 194, Wp = 194;
constexpr int PLANE = Hp * Wp;            // 37636
constexpr int NCIN = 65;                  // 64 x-channels + depth
constexpr int Lv = Hv * Wv;               // 36864
constexpr int XP_SZ  = Bv * NCIN * PLANE; // padded input elements (bf16)
constexpr int NMETA  = Bv * 9 * Lv;       // 663552

typedef __attribute__((ext_vector_type(8))) short short8;
typedef __attribute__((ext_vector_type(4))) float f32x4;
typedef unsigned short u16;

__device__ __forceinline__ u16 f2b(float v) {
  unsigned u = __float_as_uint(v);
  u = (u + 0x7FFFu + ((u >> 16) & 1u)) >> 16;   // RNE
  return (u16)u;
}
__device__ __forceinline__ float b2f(u16 u) {
  return __uint_as_float(((unsigned)u) << 16);
}

// ---------------- K0: build padded bf16 input ----------------
__global__ __launch_bounds__(256) void pad_kernel(
    const float* __restrict__ x, const float* __restrict__ depth,
    u16* __restrict__ xp) {
  for (int idx = blockIdx.x * blockDim.x + threadIdx.x; idx < XP_SZ;
       idx += gridDim.x * blockDim.x) {
    int p  = idx % PLANE;
    int bc = idx / PLANE;
    int c  = bc % NCIN;
    int b  = bc / NCIN;
    int ph = p / Wp, pw = p % Wp;
    float v = 0.f;
    if (ph >= 1 && ph <= Hv && pw >= 1 && pw <= Wv) {
      int ih = ph - 1, iw = pw - 1;
      v = (c < Cv) ? x[((b * Cv + c) * Hv + ih) * Wv + iw]
                   : depth[(b * Hv + ih) * Wv + iw];
    }
    xp[idx] = f2b(v);
  }
}

// ---------------- K0b: prep weights -> bf16 ----------------
// Wb[o][t*64+c] = bf16(W[o][c*9+t])   (main GEMM A, t-major K)
// Woffb[o][k]   = bf16(wo[o*585+k]) for o<18,k<585 else 0  (offconv A, c-major K)
__global__ __launch_bounds__(256) void prep_kernel(
    const float* __restrict__ Wg, const float* __restrict__ wo,
    u16* __restrict__ Wb, u16* __restrict__ Woffb) {
  int n = blockIdx.x * 256 + threadIdx.x;
  if (n < 64 * 576) {
    int o = n / 576, r = n % 576;
    int t = r >> 6, c = r & 63;
    Wb[n] = f2b(Wg[o * 576 + c * 9 + t]);
  }
  if (n < 32 * 640) {
    int o = n / 640, k = n % 640;
    Woffb[n] = (o < 18 && k < 585) ? f2b(wo[o * 585 + k]) : (u16)0;
  }
}

// ---------------- K1: offset conv as MFMA GEMM + fused meta --------------
// out18[18, B*L] = Woffb[18,585(->640)] x im2col0[585, B*L]; epilogue
// computes clamp/floor/frac -> midx/mfxy. Block: 64 px, M=32, 4 waves.
__global__ __launch_bounds__(256) void offconv_kernel(
    const u16* __restrict__ xp, const u16* __restrict__ Woffb,
    const float* __restrict__ bias, int* __restrict__ midx,
    float2* __restrict__ mfxy) {
  int bid = blockIdx.x;
  int swz = (bid & 7) * 144 + (bid >> 3);   // 1152 % 8 == 0, bijective
  int b   = swz / 576;
  int l0  = (swz % 576) * 64;

  __shared__ u16   s_cols[2][8][64][8];     // 16 KB
  __shared__ float s_off[18][64];           // 4.5 KB

  int tid  = threadIdx.x;
  int lane = tid & 63;
  int iq   = __builtin_amdgcn_readfirstlane(tid >> 6);
  int mw   = iq >> 1;                       // m-tile (o rows 0-15 / 16-31)
  int nw   = iq & 1;                        // n-half (px 0-31 / 32-63)

  // per-thread fixed staging coords (2 subsets of 256)
  int mi0s[2], gis[2], pxs[2];
#pragma unroll
  for (int s = 0; s < 2; ++s) {
    int idx = s * 256 + tid;
    int gi = idx >> 6, px = idx & 63;
    int l  = l0 + px;
    int oh = ((l >> 6) * 683) >> 11;        // l/192 exact (l<36864)
    int ow = l - oh * 192;
    gis[s] = gi; pxs[s] = px;
    mi0s[s] = oh * Wp + ow;                 // top-left tap of 3x3 window
  }
  const u16* xbb = xp + (size_t)(b * NCIN) * PLANE;

  auto stage = [&](int ch, int buf) {
#pragma unroll
    for (int s = 0; s < 2; ++s) {
      int k0 = ch * 64 + gis[s] * 8;
      short8 hv;
#pragma unroll
      for (int j = 0; j < 8; ++j) {
        int k = k0 + j;
        int c = (k * 7282) >> 16;           // k/9 exact (k<640)
        int t = k - c * 9;
        c = min(c, 64);                     // pad-k -> depth plane (finite)
        int th = (t * 11) >> 5;             // t/3
        int tw = t - 3 * th;
        hv[j] = (short)xbb[c * PLANE + mi0s[s] + th * Wp + tw];
      }
      *(short8*)&s_cols[buf][gis[s]][pxs[s]][0] = hv;
    }
  };

  f32x4 acc[2];
  acc[0] = (f32x4)0.f;
  acc[1] = (f32x4)0.f;

  stage(0, 0);
  __syncthreads();

  for (int ch = 0; ch < 10; ++ch) {
    int cur = ch & 1;
    if (ch < 9) stage(ch + 1, cur ^ 1);
#pragma unroll
    for (int ks = 0; ks < 2; ++ks) {
      int k = ch * 64 + ks * 32 + (lane >> 4) * 8;
      short8 a = *(const short8*)&Woffb[(mw * 16 + (lane & 15)) * 640 + k];
      int kg = ks * 4 + (lane >> 4);
      short8 b0 = *(const short8*)&s_cols[cur][kg][nw * 32 + (lane & 15)][0];
      short8 b1 = *(const short8*)&s_cols[cur][kg][nw * 32 + 16 + (lane & 15)][0];
      acc[0] = __builtin_amdgcn_mfma_f32_16x16x32_bf16(a, b0, acc[0], 0, 0, 0);
      acc[1] = __builtin_amdgcn_mfma_f32_16x16x32_bf16(a, b1, acc[1], 0, 0, 0);
    }
    __syncthreads();
  }

  // ---- write useful acc rows (o<18) to LDS ----
  int rr = lane >> 4, cl = lane & 15;
#pragma unroll
  for (int sub = 0; sub < 2; ++sub)
#pragma unroll
    for (int j = 0; j < 4; ++j) {
      int o = mw * 16 + rr * 4 + j;
      if (o < 18) s_off[o][nw * 32 + sub * 16 + cl] = acc[sub][j];
    }
  __syncthreads();

  // ---- fused meta: offsets -> clamp/floor/frac -> midx/mfxy ----
  for (int e = tid; e < 576; e += 256) {
    int t = e >> 6, px = e & 63;
    int l = l0 + px;
    int oh = ((l >> 6) * 683) >> 11;
    int ow = l - oh * 192;
    float ox = s_off[t][px] + bias[t];
    float oy = s_off[9 + t][px] + bias[9 + t];
    int th = (t * 11) >> 5;
    int tw = t - 3 * th;
    float cx = (float)(oh + th) + ox;       // base+delta+offset
    float cy = (float)(ow + tw) + oy;
    cx = fminf(fmaxf(cx, 0.f), 193.f);
    cy = fminf(fmaxf(cy, 0.f), 193.f);
    int tlx = min((int)cx, 192);
    int tly = min((int)cy, 192);
    midx[(b * 9 + t) * Lv + l] = tlx * Wp + tly;
    mfxy[(b * 9 + t) * Lv + l] =
        make_float2(cx - (float)tlx, cy - (float)tly);
  }
}

// ---------------- K2: fused gather(bf16) + MFMA, 32-px tiles -------------
__global__ __launch_bounds__(256) void main_kernel(
    const u16* __restrict__ xp, const u16* __restrict__ Wb,
    const int* __restrict__ midx, const float2* __restrict__ mfxy,
    float* __restrict__ out) {
  int bid = blockIdx.x;
  int swz = (bid & 7) * 288 + (bid >> 3);   // 2304 % 8 == 0, bijective
  int b   = swz / 1152;
  int l0  = (swz % 1152) * 32;

  __shared__ int    s_mi[9 * 32];
  __shared__ float4 s_w4[9 * 32];
  __shared__ u16    s_cols[2][8][32][8];    // 8 KB

  int tid = threadIdx.x;

  // ---- staging: metadata -> bilinear weights ----
  for (int e = tid; e < 288; e += 256) {
    int t = e >> 5, pxl = e & 31;
    int l = l0 + pxl;
    int    mi = midx[(b * 9 + t) * Lv + l];
    float2 f  = mfxy[(b * 9 + t) * Lv + l];
    float ax = 1.f - f.x, ay = 1.f - f.y;
    s_mi[e] = mi;
    s_w4[e] = make_float4(ax * ay, ax * f.y, f.x * ay, f.x * f.y);
  }

  int px   = tid & 31;
  int cg   = tid >> 5;               // channel-octet 0..7
  int lane = tid & 63;
  int iq   = __builtin_amdgcn_readfirstlane(tid >> 6);
  int o0   = iq * 16;
  const u16* xb = xp + (size_t)(b * NCIN + cg * 8) * PLANE;

  f32x4 acc[2];
  acc[0] = (f32x4)0.f;
  acc[1] = (f32x4)0.f;

  __syncthreads();

  // ---- prologue: gather chunk 0 ----
  {
    int    mi = s_mi[px];
    float4 w  = s_w4[px];
    short8 hv;
#pragma unroll
    for (int j = 0; j < 8; ++j) {
      const u16* cp = xb + j * PLANE;
      float v = w.x * b2f(cp[mi])      + w.y * b2f(cp[mi + 1]) +
                w.z * b2f(cp[mi + Wp]) + w.w * b2f(cp[mi + Wp + 1]);
      hv[j] = (short)f2b(v);
    }
    *(short8*)&s_cols[0][cg][px][0] = hv;
  }
  __syncthreads();

  for (int ch = 0; ch < 9; ++ch) {
    int cur = ch & 1;
    int    mi = 0;
    float4 w  = make_float4(0.f, 0.f, 0.f, 0.f);
    u16    pr[4][4];

    // ---- T14 phase A: first-half loads of chunk ch+1 ----
    if (ch < 8) {
      mi = s_mi[(ch + 1) * 32 + px];
      w  = s_w4[(ch + 1) * 32 + px];
#pragma unroll
      for (int j = 0; j < 4; ++j) {
        const u16* cp = xb + j * PLANE;
        pr[j][0] = cp[mi];      pr[j][1] = cp[mi + 1];
        pr[j][2] = cp[mi + Wp]; pr[j][3] = cp[mi + Wp + 1];
      }
    }

    // ---- MFMA on buf[cur] ----
#pragma unroll
    for (int ks = 0; ks < 2; ++ks) {
      int k = ch * 64 + ks * 32 + (lane >> 4) * 8;
      short8 a  = *(const short8*)&Wb[(o0 + (lane & 15)) * 576 + k];
      int kg = ks * 4 + (lane >> 4);
      short8 b0 = *(const short8*)&s_cols[cur][kg][lane & 15][0];
      short8 b1 = *(const short8*)&s_cols[cur][kg][16 + (lane & 15)][0];
      acc[0] = __builtin_amdgcn_mfma_f32_16x16x32_bf16(a, b0, acc[0], 0, 0, 0);
      acc[1] = __builtin_amdgcn_mfma_f32_16x16x32_bf16(a, b1, acc[1], 0, 0, 0);
    }

    // ---- T14 phase B: second-half loads, lerp, write ----
    if (ch < 8) {
      u16 sr[4][4];
#pragma unroll
      for (int j = 0; j < 4; ++j) {
        const u16* cp = xb + (4 + j) * PLANE;
        sr[j][0] = cp[mi];      sr[j][1] = cp[mi + 1];
        sr[j][2] = cp[mi + Wp]; sr[j][3] = cp[mi + Wp + 1];
      }
      short8 hv;
#pragma unroll
      for (int j = 0; j < 4; ++j)
        hv[j] = (short)f2b(w.x * b2f(pr[j][0]) + w.y * b2f(pr[j][1]) +
                           w.z * b2f(pr[j][2]) + w.w * b2f(pr[j][3]));
#pragma unroll
      for (int j = 0; j < 4; ++j)
        hv[4 + j] = (short)f2b(w.x * b2f(sr[j][0]) + w.y * b2f(sr[j][1]) +
                               w.z * b2f(sr[j][2]) + w.w * b2f(sr[j][3]));
      *(short8*)&s_cols[cur ^ 1][cg][px][0] = hv;
    }
    __syncthreads();
  }

  // ---- epilogue: D[o][px], row=(lane>>4)*4+j, col=lane&15 ----
  int rr = lane >> 4, cl = lane & 15;
#pragma unroll
  for (int nt = 0; nt < 2; ++nt)
#pragma unroll
    for (int j = 0; j < 4; ++j) {
      int o = o0 + rr * 4 + j;
      int l = l0 + nt * 16 + cl;
      out[((size_t)(b * Cv + o)) * Lv + l] = acc[nt][j];
    }
}

// ---------------- launch ----------------
extern "C" void kernel_launch(void* const* d_in, const int* in_sizes, int n_in,
                              void* d_out, int out_size, void* d_ws, size_t ws_size,
                              hipStream_t stream) {
  const float* x     = (const float*)d_in[0];
  const float* depth = (const float*)d_in[1];
  const float* wo    = (const float*)d_in[2];
  const float* bias  = (const float*)d_in[3];
  const float* wgt   = (const float*)d_in[4];
  float* out = (float*)d_out;

  // ws layout (all 16B-aligned)
  u16* xp16    = (u16*)d_ws;                        // XP_SZ u16
  int* midx    = (int*)(xp16 + XP_SZ);              // NMETA int
  float2* mfxy = (float2*)(midx + NMETA);           // NMETA float2
  u16* Wb      = (u16*)(mfxy + NMETA);              // 64*576
  u16* Woffb   = Wb + 64 * 576;                     // 32*640

  pad_kernel<<<2048, 256, 0, stream>>>(x, depth, xp16);
  prep_kernel<<<144, 256, 0, stream>>>(wgt, wo, Wb, Woffb);
  offconv_kernel<<<1152, 256, 0, stream>>>(xp16, Woffb, bias, midx, mfxy);
  main_kernel<<<2304, 256, 0, stream>>>(xp16, Wb, midx, mfxy, out);
}

// Round 8
// 188.414 us; speedup vs baseline: 1.1789x; 1.0066x over previous
//
#include <hip/hip_runtime.h>

// ---------------- problem constants ----------------
constexpr int Bv = 2, Cv = 64, Hv = 192, Wv = 192;
constexpr int Hp = 194, Wp = 194;
constexpr int PLANE = Hp * Wp;            // 37636
constexpr int NCIN = 65;                  // 64 x-channels + depth
constexpr int Lv = Hv * Wv;               // 36864
constexpr int XP_SZ  = Bv * NCIN * PLANE; // padded input elements (bf16)

typedef __attribute__((ext_vector_type(8))) short short8;
typedef __attribute__((ext_vector_type(4))) float f32x4;
typedef unsigned short u16;

__device__ __forceinline__ u16 f2b(float v) {
  unsigned u = __float_as_uint(v);
  u = (u + 0x7FFFu + ((u >> 16) & 1u)) >> 16;   // RNE
  return (u16)u;
}
__device__ __forceinline__ float b2f(u16 u) {
  return __uint_as_float(((unsigned)u) << 16);
}

// ---------------- K0: build padded bf16 input ----------------
__global__ __launch_bounds__(256) void pad_kernel(
    const float* __restrict__ x, const float* __restrict__ depth,
    u16* __restrict__ xp) {
  for (int idx = blockIdx.x * blockDim.x + threadIdx.x; idx < XP_SZ;
       idx += gridDim.x * blockDim.x) {
    int p  = idx % PLANE;
    int bc = idx / PLANE;
    int c  = bc % NCIN;
    int b  = bc / NCIN;
    int ph = p / Wp, pw = p % Wp;
    float v = 0.f;
    if (ph >= 1 && ph <= Hv && pw >= 1 && pw <= Wv) {
      int ih = ph - 1, iw = pw - 1;
      v = (c < Cv) ? x[((b * Cv + c) * Hv + ih) * Wv + iw]
                   : depth[(b * Hv + ih) * Wv + iw];
    }
    xp[idx] = f2b(v);
  }
}

// ---------------- K0b: prep weights -> bf16 ----------------
// Wb[o][t*64+c] = bf16(W[o][c*9+t])   (main GEMM A, t-major K)
// Woffb[o][k]   = bf16(wo[o*585+k]) for o<18,k<585 else 0  (offset A)
__global__ __launch_bounds__(256) void prep_kernel(
    const float* __restrict__ Wg, const float* __restrict__ wo,
    u16* __restrict__ Wb, u16* __restrict__ Woffb) {
  int n = blockIdx.x * 256 + threadIdx.x;
  if (n < 64 * 576) {
    int o = n / 576, r = n % 576;
    int t = r >> 6, c = r & 63;
    Wb[n] = f2b(Wg[o * 576 + c * 9 + t]);
  }
  if (n < 32 * 640) {
    int o = n / 640, k = n % 640;
    Woffb[n] = (o < 18 && k < 585) ? f2b(wo[o * 585 + k]) : (u16)0;
  }
}

// ---------------- K1: fully fused offset-GEMM + meta + gather-GEMM -------
// Block = 32 px x (all work), 4 waves.
// Phase 1: offsets[18,32px] = Woffb[18,640] x im2col0[640,32] (MFMA)
// Phase 2: meta -> s_mi / s_w4 (in LDS, no global roundtrip)
// Phase 3: deform gather + main GEMM (64 o x 32 px), T14 half-prefetch.
__global__ __launch_bounds__(256) void fused_kernel(
    const u16* __restrict__ xp, const u16* __restrict__ Wb,
    const u16* __restrict__ Woffb, const float* __restrict__ bias,
    float* __restrict__ out) {
  int bid = blockIdx.x;
  int swz = (bid & 7) * 288 + (bid >> 3);   // 2304 % 8 == 0, bijective
  int b   = swz / 1152;
  int l0  = (swz % 1152) * 32;

  __shared__ u16    s_cols[2][8][32][8];    // 8 KB (shared by both GEMMs)
  __shared__ float  s_off[18][32];          // 2.25 KB
  __shared__ int    s_mi[9 * 32];
  __shared__ float4 s_w4[9 * 32];

  int tid  = threadIdx.x;
  int lane = tid & 63;
  int iq   = __builtin_amdgcn_readfirstlane(tid >> 6);  // wave 0..3

  const u16* xbb = xp + (size_t)(b * NCIN) * PLANE;

  // ================= Phase 1: offset GEMM =================
  {
    int gi = tid >> 5, px = tid & 31;
    int l  = l0 + px;
    int oh = ((l >> 6) * 683) >> 11;        // l/192 exact (l<36864)
    int ow = l - oh * 192;
    int mi0 = oh * Wp + ow;                 // top-left of fixed 3x3 window

    auto stage0 = [&](int ch, int buf) {
      int k0 = ch * 64 + gi * 8;
      short8 hv;
#pragma unroll
      for (int j = 0; j < 8; ++j) {
        int k = k0 + j;
        int c = (k * 7282) >> 16;           // k/9 exact (k<3640)
        int t = k - c * 9;
        c = min(c, 64);                     // pad-k -> depth plane (finite)
        int th = (t * 11) >> 5;             // t/3
        int tw = t - 3 * th;
        hv[j] = (short)xbb[c * PLANE + mi0 + th * Wp + tw];
      }
      *(short8*)&s_cols[buf][gi][px][0] = hv;
    };

    f32x4 oacc = (f32x4)0.f;
    int mw = iq >> 1, nw = iq & 1;          // 16x16 tile per wave

    stage0(0, 0);
    __syncthreads();
    for (int ch = 0; ch < 10; ++ch) {
      int cur = ch & 1;
      if (ch < 9) stage0(ch + 1, cur ^ 1);
#pragma unroll
      for (int ks = 0; ks < 2; ++ks) {
        int k = ch * 64 + ks * 32 + (lane >> 4) * 8;
        short8 a  = *(const short8*)&Woffb[(mw * 16 + (lane & 15)) * 640 + k];
        int kg = ks * 4 + (lane >> 4);
        short8 bb = *(const short8*)&s_cols[cur][kg][nw * 16 + (lane & 15)][0];
        oacc = __builtin_amdgcn_mfma_f32_16x16x32_bf16(a, bb, oacc, 0, 0, 0);
      }
      __syncthreads();
    }

    // write useful rows (o<18) to LDS
    int rr = lane >> 4, cl = lane & 15;
#pragma unroll
    for (int j = 0; j < 4; ++j) {
      int o = mw * 16 + rr * 4 + j;
      if (o < 18) s_off[o][nw * 16 + cl] = oacc[j];
    }
  }
  __syncthreads();

  // ================= Phase 2: meta =================
  for (int e = tid; e < 288; e += 256) {
    int t = e >> 5, pxl = e & 31;
    int l = l0 + pxl;
    int oh = ((l >> 6) * 683) >> 11;
    int ow = l - oh * 192;
    float ox = s_off[t][pxl] + bias[t];
    float oy = s_off[9 + t][pxl] + bias[9 + t];
    int th = (t * 11) >> 5;
    int tw = t - 3 * th;
    float cx = (float)(oh + th) + ox;       // base+delta+offset
    float cy = (float)(ow + tw) + oy;
    cx = fminf(fmaxf(cx, 0.f), 193.f);
    cy = fminf(fmaxf(cy, 0.f), 193.f);
    int tlx = min((int)cx, 192);
    int tly = min((int)cy, 192);
    float fx = cx - (float)tlx, fy = cy - (float)tly;
    float ax = 1.f - fx, ay = 1.f - fy;
    s_mi[e] = tlx * Wp + tly;
    s_w4[e] = make_float4(ax * ay, ax * fy, fx * ay, fx * fy);
  }
  __syncthreads();

  // ================= Phase 3: deform gather + main GEMM =================
  int px = tid & 31;
  int cg = tid >> 5;                 // channel-octet 0..7
  int o0 = iq * 16;
  const u16* xb = xbb + (size_t)(cg * 8) * PLANE;

  f32x4 acc[2];
  acc[0] = (f32x4)0.f;
  acc[1] = (f32x4)0.f;

  // prologue: gather chunk 0
  {
    int    mi = s_mi[px];
    float4 w  = s_w4[px];
    short8 hv;
#pragma unroll
    for (int j = 0; j < 8; ++j) {
      const u16* cp = xb + j * PLANE;
      float v = w.x * b2f(cp[mi])      + w.y * b2f(cp[mi + 1]) +
                w.z * b2f(cp[mi + Wp]) + w.w * b2f(cp[mi + Wp + 1]);
      hv[j] = (short)f2b(v);
    }
    *(short8*)&s_cols[0][cg][px][0] = hv;
  }
  __syncthreads();

  for (int ch = 0; ch < 9; ++ch) {
    int cur = ch & 1;
    int    mi = 0;
    float4 w  = make_float4(0.f, 0.f, 0.f, 0.f);
    u16    pr[4][4];

    // T14 phase A: first-half loads of chunk ch+1
    if (ch < 8) {
      mi = s_mi[(ch + 1) * 32 + px];
      w  = s_w4[(ch + 1) * 32 + px];
#pragma unroll
      for (int j = 0; j < 4; ++j) {
        const u16* cp = xb + j * PLANE;
        pr[j][0] = cp[mi];      pr[j][1] = cp[mi + 1];
        pr[j][2] = cp[mi + Wp]; pr[j][3] = cp[mi + Wp + 1];
      }
    }

    // MFMA on buf[cur]
#pragma unroll
    for (int ks = 0; ks < 2; ++ks) {
      int k = ch * 64 + ks * 32 + (lane >> 4) * 8;
      short8 a  = *(const short8*)&Wb[(o0 + (lane & 15)) * 576 + k];
      int kg = ks * 4 + (lane >> 4);
      short8 b0 = *(const short8*)&s_cols[cur][kg][lane & 15][0];
      short8 b1 = *(const short8*)&s_cols[cur][kg][16 + (lane & 15)][0];
      acc[0] = __builtin_amdgcn_mfma_f32_16x16x32_bf16(a, b0, acc[0], 0, 0, 0);
      acc[1] = __builtin_amdgcn_mfma_f32_16x16x32_bf16(a, b1, acc[1], 0, 0, 0);
    }

    // T14 phase B: second-half loads, lerp, write
    if (ch < 8) {
      u16 sr[4][4];
#pragma unroll
      for (int j = 0; j < 4; ++j) {
        const u16* cp = xb + (4 + j) * PLANE;
        sr[j][0] = cp[mi];      sr[j][1] = cp[mi + 1];
        sr[j][2] = cp[mi + Wp]; sr[j][3] = cp[mi + Wp + 1];
      }
      short8 hv;
#pragma unroll
      for (int j = 0; j < 4; ++j)
        hv[j] = (short)f2b(w.x * b2f(pr[j][0]) + w.y * b2f(pr[j][1]) +
                           w.z * b2f(pr[j][2]) + w.w * b2f(pr[j][3]));
#pragma unroll
      for (int j = 0; j < 4; ++j)
        hv[4 + j] = (short)f2b(w.x * b2f(sr[j][0]) + w.y * b2f(sr[j][1]) +
                               w.z * b2f(sr[j][2]) + w.w * b2f(sr[j][3]));
      *(short8*)&s_cols[cur ^ 1][cg][px][0] = hv;
    }
    __syncthreads();
  }

  // epilogue: D[o][px], row=(lane>>4)*4+j, col=lane&15
  int rr = lane >> 4, cl = lane & 15;
#pragma unroll
  for (int nt = 0; nt < 2; ++nt)
#pragma unroll
    for (int j = 0; j < 4; ++j) {
      int o = o0 + rr * 4 + j;
      int l = l0 + nt * 16 + cl;
      out[((size_t)(b * Cv + o)) * Lv + l] = acc[nt][j];
    }
}

// ---------------- launch ----------------
extern "C" void kernel_launch(void* const* d_in, const int* in_sizes, int n_in,
                              void* d_out, int out_size, void* d_ws, size_t ws_size,
                              hipStream_t stream) {
  const float* x     = (const float*)d_in[0];
  const float* depth = (const float*)d_in[1];
  const float* wo    = (const float*)d_in[2];
  const float* bias  = (const float*)d_in[3];
  const float* wgt   = (const float*)d_in[4];
  float* out = (float*)d_out;

  u16* xp16  = (u16*)d_ws;                          // XP_SZ u16
  u16* Wb    = xp16 + XP_SZ;                        // 64*576
  u16* Woffb = Wb + 64 * 576;                       // 32*640

  pad_kernel<<<2048, 256, 0, stream>>>(x, depth, xp16);
  prep_kernel<<<144, 256, 0, stream>>>(wgt, wo, Wb, Woffb);
  fused_kernel<<<2304, 256, 0, stream>>>(xp16, Wb, Woffb, bias, out);
}